// Round 3
// baseline (241.874 us; speedup 1.0000x reference)
//
#include <hip/hip_runtime.h>

// NCC (local normalized cross-correlation) loss, win=9^3, SAME zero padding.
// Volume: (B=2, C=1, D=160, H=192, W=160) fp32. Output: scalar fp32 loss.
//
// v3: occupancy-first redesign.
//  - ZC=9 z-chunks -> 4320 blocks (~17/CU) instead of 480 (~1.9/CU)
//  - ring buffer of 9 z-slices in registers, z-loop FULLY unrolled so ring
//    slot (so+8)%9 is compile-time (no shift movs, no scratch)
//  - 1 global load per column per step (no departing-slice re-read)
//  - next-slice loads issued right after first barrier (hide under LDS phases)
//  - padded LDS strides (Zq row stride 28; Rq q-stride 496 -> paired q's on
//    disjoint bank halves; Sq stride 17) for ~conflict-free access
//  - Sq aliases Zq (dead after x-phase) -> 23.4 KB LDS -> 6 blocks/CU (75%)
//  - deterministic two-stage reduction through d_ws

#define NX 160
#define NY 192
#define NZ 160
#define NB 2
#define SLICE (NX * NY)           // 30720
#define VOL   (SLICE * NZ)        // 4915200
#define TOTAL (VOL * NB)          // 9830400

#define TX 16
#define TY 16
#define ZC 9
#define GX (NX / TX)              // 10
#define GY (NY / TY)              // 12
#define GZ 18                     // 18*9 = 162 >= 160 (last chunk tail-guarded)
#define NPART (GX * GY * GZ * NB) // 4320

#define HALO 24                   // TX + 8
#define NCOL (HALO * HALO)        // 576
#define ZQS 28                    // Zq row stride (words)
#define ZQQ (HALO * ZQS)          // 672 words per quantity plane
#define RQS 20                    // Rq row stride (words)
#define RQQ (HALO * RQS + 16)     // 496: +16 pad puts q,q+1 on disjoint bank halves
#define SQS 17                    // Sq row stride (words)
#define SQQ (TY * SQS)            // 272
#define INV729 (1.0f / 729.0f)

__global__ __launch_bounds__(256, 6) void ncc_main(
    const float* __restrict__ J_pred,   // predict
    const float* __restrict__ I_targ,   // target
    float* __restrict__ partial)
{
    const int tid = threadIdx.x;
    const int x0 = blockIdx.x * TX;
    const int y0 = blockIdx.y * TY;
    const int b  = blockIdx.z / GZ;
    const int z0 = (blockIdx.z % GZ) * ZC;

    __shared__ __align__(16) float Zq[5 * ZQQ];   // 13440 B; re-used as Sq in phase 3/4
    __shared__ __align__(16) float Rq[5 * RQQ];   //  9920 B
    __shared__ float redbuf[4];
    float* const Sq = Zq;   // alias: Zq is dead after phase 2 reads (barrier-separated)

    // ---- column ownership: c = tid, tid+256, tid+512 (<576), scalar columns ----
    int  cbase[3], cldst[3];
    bool cexist[3], cvalid[3];
#pragma unroll
    for (int ci = 0; ci < 3; ++ci) {
        const int c  = tid + ci * 256;
        const int r  = c / HALO;
        const int x  = c - r * HALO;
        const int gy = y0 - 4 + r;
        const int gx = x0 - 4 + x;
        cexist[ci] = (c < NCOL);
        cvalid[ci] = cexist[ci] && ((unsigned)gy < (unsigned)NY) && ((unsigned)gx < (unsigned)NX);
        cbase[ci]  = cvalid[ci] ? (gy * NX + gx) : 0;
        cldst[ci]  = r * ZQS + x;
    }
    const size_t bvol = (size_t)b * VOL;

    // ---- ring of 9 z-slices + 5 running z-box-sums (all statically indexed) ----
    float ringI[3][9], ringJ[3][9], run[3][5];
#pragma unroll
    for (int ci = 0; ci < 3; ++ci) {
#pragma unroll
        for (int k = 0; k < 9; ++k) { ringI[ci][k] = 0.f; ringJ[ci][k] = 0.f; }
#pragma unroll
        for (int q = 0; q < 5; ++q) run[ci][q] = 0.f;
    }

    float pI[3], pJ[3];   // pending (prefetched) slice values
    auto load_slice = [&](int zin) {
        const bool  zok  = ((unsigned)zin < (unsigned)NZ);
        const size_t zoff = bvol + (size_t)zin * SLICE;
#pragma unroll
        for (int ci = 0; ci < 3; ++ci) {
            float iv = 0.f, jv = 0.f;
            if (zok && cvalid[ci]) {
                iv = I_targ[zoff + cbase[ci]];
                jv = J_pred[zoff + cbase[ci]];
            }
            pI[ci] = iv; pJ[ci] = jv;
        }
    };

    // ---- warmup: slices z0-4 .. z0+3 fill ring slots 0..7 (OOB z -> zeros) ----
#pragma unroll
    for (int s = 0; s < 8; ++s) {
        load_slice(z0 - 4 + s);
#pragma unroll
        for (int ci = 0; ci < 3; ++ci) {
            const float iN = pI[ci], jN = pJ[ci];
            run[ci][0] += iN;      run[ci][1] += jN;
            run[ci][2] += iN * iN; run[ci][3] += jN * jN; run[ci][4] += iN * jN;
            ringI[ci][s] = iN;     ringJ[ci][s] = jN;
        }
    }
    load_slice(z0 + 4);   // pending for so = 0

    const int ty = tid >> 4, tx = tid & 15;
    float acc = 0.f;

#pragma unroll
    for (int so = 0; so < ZC; ++so) {
        const int slot = (so + 8) % 9;   // compile-time constant (full unroll)

        // phase 0: consume pending slice z0+4+so, slide z-window
#pragma unroll
        for (int ci = 0; ci < 3; ++ci) {
            const float iN = pI[ci], jN = pJ[ci];
            const float i0 = ringI[ci][slot], j0 = ringJ[ci][slot];
            run[ci][0] += iN - i0;
            run[ci][1] += jN - j0;
            run[ci][2] += iN * iN - i0 * i0;
            run[ci][3] += jN * jN - j0 * j0;
            run[ci][4] += iN * jN - i0 * j0;
            ringI[ci][slot] = iN; ringJ[ci][slot] = jN;
        }

        // phase 1: stage z-sums to LDS
#pragma unroll
        for (int ci = 0; ci < 3; ++ci) {
            if (cexist[ci]) {
#pragma unroll
                for (int q = 0; q < 5; ++q) Zq[q * ZQQ + cldst[ci]] = run[ci][q];
            }
        }
        __syncthreads();

        // prefetch next slice — latency hides under phases 2-4
        if (so < ZC - 1) load_slice(z0 + 5 + so);

        // phase 2: x-boxsum, 240 tasks = 24 rows x 5 q x 2 halves (sliding)
        if (tid < 240) {
            const int q   = tid / 48;
            const int rem = tid - q * 48;
            const int row = rem >> 1;
            const int h   = rem & 1;
            const float* src = &Zq[q * ZQQ + row * ZQS + h * 8];
            const float4 v0 = *(const float4*)(src + 0);
            const float4 v1 = *(const float4*)(src + 4);
            const float4 v2 = *(const float4*)(src + 8);
            const float4 v3 = *(const float4*)(src + 12);
            const float c_[16] = { v0.x, v0.y, v0.z, v0.w, v1.x, v1.y, v1.z, v1.w,
                                   v2.x, v2.y, v2.z, v2.w, v3.x, v3.y, v3.z, v3.w };
            float s = c_[0] + c_[1] + c_[2] + c_[3] + c_[4]
                    + c_[5] + c_[6] + c_[7] + c_[8];
            float o[8];
            o[0] = s;
#pragma unroll
            for (int i = 1; i < 8; ++i) { s += c_[i + 8] - c_[i - 1]; o[i] = s; }
            float* dst = &Rq[q * RQQ + row * RQS + h * 8];
            *(float4*)(dst + 0) = make_float4(o[0], o[1], o[2], o[3]);
            *(float4*)(dst + 4) = make_float4(o[4], o[5], o[6], o[7]);
        }
        __syncthreads();

        // phase 3: y-boxsum sliding, 160 tasks = 5 q x 16 cols x 2 halves -> Sq (=Zq)
        if (tid < 160) {
            const int q   = tid / 32;
            const int r2  = tid - q * 32;
            const int tcx = r2 >> 1;
            const int h   = r2 & 1;
            float c_[16];
#pragma unroll
            for (int k = 0; k < 16; ++k) c_[k] = Rq[q * RQQ + (h * 8 + k) * RQS + tcx];
            float s = c_[0] + c_[1] + c_[2] + c_[3] + c_[4]
                    + c_[5] + c_[6] + c_[7] + c_[8];
            Sq[q * SQQ + (h * 8) * SQS + tcx] = s;
#pragma unroll
            for (int i = 1; i < 8; ++i) {
                s += c_[i + 8] - c_[i - 1];
                Sq[q * SQQ + (h * 8 + i) * SQS + tcx] = s;
            }
        }
        __syncthreads();

        // phase 4: cc per output voxel
        const float S0 = Sq[0 * SQQ + ty * SQS + tx];
        const float S1 = Sq[1 * SQQ + ty * SQS + tx];
        const float S2 = Sq[2 * SQQ + ty * SQS + tx];
        const float S3 = Sq[3 * SQQ + ty * SQS + tx];
        const float S4 = Sq[4 * SQQ + ty * SQS + tx];
        const float cross = S4 - S0 * S1 * INV729;
        const float Iv    = S2 - S0 * S0 * INV729;
        const float Jv    = S3 - S1 * S1 * INV729;
        const float cc    = (cross * cross) / (Iv * Jv + 1e-5f);
        if (z0 + so < NZ) acc += cc;   // tail guard for last z-chunk (162 > 160)

        __syncthreads();   // Sq (=Zq) reads must precede next step's Zq writes
    }

    // ---- block reduction (deterministic within block) ----
#pragma unroll
    for (int off = 32; off > 0; off >>= 1) acc += __shfl_down(acc, off);
    if ((tid & 63) == 0) redbuf[tid >> 6] = acc;
    __syncthreads();
    if (tid == 0) {
        const int bid = blockIdx.x + GX * (blockIdx.y + GY * blockIdx.z);
        partial[bid] = redbuf[0] + redbuf[1] + redbuf[2] + redbuf[3];
    }
}

__global__ __launch_bounds__(256) void ncc_final(
    const float* __restrict__ partial, float* __restrict__ out)
{
    __shared__ float sm[256];
    const int tid = threadIdx.x;
    float s = 0.f;
    for (int i = tid; i < NPART; i += 256) s += partial[i];
    sm[tid] = s;
    __syncthreads();
#pragma unroll
    for (int w = 128; w > 0; w >>= 1) {
        if (tid < w) sm[tid] += sm[tid + w];
        __syncthreads();
    }
    if (tid == 0) out[0] = 1.0f - sm[0] * (1.0f / (float)TOTAL);
}

extern "C" void kernel_launch(void* const* d_in, const int* in_sizes, int n_in,
                              void* d_out, int out_size, void* d_ws, size_t ws_size,
                              hipStream_t stream)
{
    const float* predict = (const float*)d_in[0];  // J
    const float* target  = (const float*)d_in[1];  // I
    float* partial = (float*)d_ws;                 // 4320 floats (17.3 KB)

    dim3 grid(GX, GY, GZ * NB);
    ncc_main<<<grid, 256, 0, stream>>>(predict, target, partial);
    ncc_final<<<1, 256, 0, stream>>>(partial, (float*)d_out);
}

// Round 4
// 82.709 us; speedup vs baseline: 2.9244x; 2.9244x over previous
//
#include <hip/hip_runtime.h>

// NCC (local normalized cross-correlation) loss, win=9^3, SAME zero padding.
// Volume: (B=2, C=1, D=160, H=192, W=160) fp32. Output: scalar fp32 loss.
//
// v4: latency-tolerant fused single pass.
//  - lgkm-only barriers (raw s_barrier + s_waitcnt lgkmcnt(0)): __syncthreads
//    drains vmcnt(0) on hipcc, killing any prefetch; raw barriers let the
//    next-slice global loads stay in flight across the whole step.
//  - ZC=16 -> 2400 blocks (~9.4/CU), z-halo ratio 1.5 (v3's ZC=9 was 1.89
//    and fetch-bound at 638 MB).
//  - float4 column loads: 144 tasks x 4 columns, gx 4-aligned, rows are
//    160 B contiguous runs; departing slice re-loaded (L2-hot) -> no ring,
//    ~60 VGPR, rolled z-loop.
//  - LDS 26.9 KB (Zq stride 28, Rq stride 16 + 16-word q-pad, Sq stride 17)
//    -> 6 blocks/CU resident; XCD-chunked block swizzle (2400%8==0).
//  - deterministic two-stage reduction through d_ws.

#define NX 160
#define NY 192
#define NZ 160
#define NB 2
#define SLICE (NX * NY)            // 30720
#define VOL   (SLICE * NZ)         // 4915200
#define TOTAL (VOL * NB)           // 9830400

#define TX 16
#define TY 16
#define ZC 16
#define GXT (NX / TX)              // 10
#define GYT (NY / TY)              // 12
#define GZT (NZ / ZC)              // 10
#define NBLK (GXT * GYT * GZT * NB) // 2400

#define HALO 24                    // TX + 8
#define ZQS 28                     // Zq row stride (words)
#define ZQQ (HALO * ZQS)           // 672 words per quantity plane
#define RQS 16                     // Rq row stride (words)
#define RQQ (HALO * RQS + 16)      // 400: pad puts q,q+1 on opposite bank halves
#define SQS 17
#define SQQ (TY * SQS)             // 272
#define INV729 (1.0f / 729.0f)

__device__ __forceinline__ void lds_barrier() {
    // LDS-visibility barrier WITHOUT vmcnt drain: prefetched global loads
    // stay in flight (hipcc's __syncthreads would emit s_waitcnt vmcnt(0)).
    asm volatile("s_waitcnt lgkmcnt(0)" ::: "memory");
    __builtin_amdgcn_s_barrier();
}

__device__ __forceinline__ float4 f4add(float4 a, float4 b) {
    return make_float4(a.x + b.x, a.y + b.y, a.z + b.z, a.w + b.w);
}
__device__ __forceinline__ float4 f4sub(float4 a, float4 b) {
    return make_float4(a.x - b.x, a.y - b.y, a.z - b.z, a.w - b.w);
}
__device__ __forceinline__ float4 f4mul(float4 a, float4 b) {
    return make_float4(a.x * b.x, a.y * b.y, a.z * b.z, a.w * b.w);
}

__global__ __launch_bounds__(256) void ncc_main(
    const float* __restrict__ J_pred,   // predict
    const float* __restrict__ I_targ,   // target
    float* __restrict__ partial)
{
    const int tid = threadIdx.x;

    // XCD-chunked swizzle: 8 XCDs x 300 consecutive logical blocks (bijective).
    const int lin = blockIdx.x;
    const int s   = (lin & 7) * (NBLK / 8) + (lin >> 3);
    const int bx  = s % GXT;
    const int r1  = s / GXT;
    const int by  = r1 % GYT;
    const int r2  = r1 / GYT;
    const int zc  = r2 % GZT;
    const int b   = r2 / GZT;

    const int x0 = bx * TX;
    const int y0 = by * TY;
    const int z0 = zc * ZC;

    __shared__ __align__(16) float Zq[5 * ZQQ];   // 13440 B
    __shared__ __align__(16) float Rq[5 * RQQ];   //  8000 B
    __shared__ float Sq[5 * SQQ];                 //  5440 B
    __shared__ float redbuf[4];

    // ---- float4 column ownership: 144 tasks = 24 rows x 6 groups ----
    const bool is_col = (tid < 144);
    const int  crow = tid / 6;           // 0..23
    const int  cq   = tid - crow * 6;    // 0..5
    const int  gy = y0 - 4 + crow;
    const int  gx = x0 - 4 + cq * 4;     // 4-aligned; fully valid or fully OOB
    const bool vxy = is_col && ((unsigned)gy < (unsigned)NY) && (gx >= 0) && (gx <= NX - 4);
    const size_t cbase = (size_t)b * VOL + (vxy ? (size_t)(gy * NX + gx) : 0);
    const float* const baseI = I_targ + cbase;
    const float* const baseJ = J_pred + cbase;

    // ---- running z-box-sums over 4 owned columns ----
    const float4 f40 = make_float4(0.f, 0.f, 0.f, 0.f);
    float4 rS0 = f40, rS1 = f40, rS2 = f40, rS3 = f40, rS4 = f40;

    // ---- warmup: add slices z0-5 .. z0+3 (9 slices; OOB z -> zeros).
    // Main loop always subtracts z0+so-5; at so=0 that removes the z0-5
    // slice added here (fp cancellation exact enough: absmax 0.0 in v2/v3).
#pragma unroll 3
    for (int ss = 0; ss < 9; ++ss) {
        const int z = z0 - 5 + ss;
        float4 aI = f40, aJ = f40;
        if (vxy && (unsigned)z < (unsigned)NZ) {
            aI = *(const float4*)(baseI + (size_t)z * SLICE);
            aJ = *(const float4*)(baseJ + (size_t)z * SLICE);
        }
        rS0 = f4add(rS0, aI);
        rS1 = f4add(rS1, aJ);
        rS2 = f4add(rS2, f4mul(aI, aI));
        rS3 = f4add(rS3, f4mul(aJ, aJ));
        rS4 = f4add(rS4, f4mul(aI, aJ));
    }

    // ---- pending (prefetched) slices for so = 0 ----
    float4 nIa = f40, nJa = f40, nIs = f40, nJs = f40;
    if (vxy) {
        const int za = z0 + 4;                 // always < NZ
        nIa = *(const float4*)(baseI + (size_t)za * SLICE);
        nJa = *(const float4*)(baseJ + (size_t)za * SLICE);
        const int zs = z0 - 5;
        if (zs >= 0) {
            nIs = *(const float4*)(baseI + (size_t)zs * SLICE);
            nJs = *(const float4*)(baseJ + (size_t)zs * SLICE);
        }
    }

    const int ty = tid >> 4, tx = tid & 15;
    float acc = 0.f;

#pragma unroll 1
    for (int so = 0; so < ZC; ++so) {
        // P0: consume pending add/sub slices, slide z-window
        rS0 = f4add(rS0, f4sub(nIa, nIs));
        rS1 = f4add(rS1, f4sub(nJa, nJs));
        rS2 = f4add(rS2, f4sub(f4mul(nIa, nIa), f4mul(nIs, nIs)));
        rS3 = f4add(rS3, f4sub(f4mul(nJa, nJa), f4mul(nJs, nJs)));
        rS4 = f4add(rS4, f4sub(f4mul(nIa, nJa), f4mul(nIs, nJs)));

        // issue next step's loads NOW — they stay in flight across all three
        // lgkm-only barriers and are consumed at the next P0.
        nIa = f40; nJa = f40; nIs = f40; nJs = f40;
        if (so < ZC - 1 && vxy) {
            const int za = z0 + 5 + so;
            if (za < NZ) {
                nIa = *(const float4*)(baseI + (size_t)za * SLICE);
                nJa = *(const float4*)(baseJ + (size_t)za * SLICE);
            }
            const int zs = z0 + so - 4;
            if (zs >= 0) {   // zs <= z0+10 < NZ always
                nIs = *(const float4*)(baseI + (size_t)zs * SLICE);
                nJs = *(const float4*)(baseJ + (size_t)zs * SLICE);
            }
        }

        // P1: stage z-sums (float4 writes; zeros for invalid cols)
        if (is_col) {
            const int o = crow * ZQS + cq * 4;
            *(float4*)&Zq[0 * ZQQ + o] = rS0;
            *(float4*)&Zq[1 * ZQQ + o] = rS1;
            *(float4*)&Zq[2 * ZQQ + o] = rS2;
            *(float4*)&Zq[3 * ZQQ + o] = rS3;
            *(float4*)&Zq[4 * ZQQ + o] = rS4;
        }
        lds_barrier();

        // P2: x-boxsum, 240 tasks = 24 rows x 5 q x 2 halves (sliding)
        if (tid < 240) {
            const int q   = tid / 48;
            const int rem = tid - q * 48;
            const int row = rem >> 1;
            const int h   = rem & 1;
            const float* src = &Zq[q * ZQQ + row * ZQS + h * 8];
            const float4 v0 = *(const float4*)(src + 0);
            const float4 v1 = *(const float4*)(src + 4);
            const float4 v2 = *(const float4*)(src + 8);
            const float4 v3 = *(const float4*)(src + 12);
            const float c_[16] = { v0.x, v0.y, v0.z, v0.w, v1.x, v1.y, v1.z, v1.w,
                                   v2.x, v2.y, v2.z, v2.w, v3.x, v3.y, v3.z, v3.w };
            float sx = c_[0] + c_[1] + c_[2] + c_[3] + c_[4]
                     + c_[5] + c_[6] + c_[7] + c_[8];
            float o[8];
            o[0] = sx;
#pragma unroll
            for (int i = 1; i < 8; ++i) { sx += c_[i + 8] - c_[i - 1]; o[i] = sx; }
            float* dst = &Rq[q * RQQ + row * RQS + h * 8];
            *(float4*)(dst + 0) = make_float4(o[0], o[1], o[2], o[3]);
            *(float4*)(dst + 4) = make_float4(o[4], o[5], o[6], o[7]);
        }
        lds_barrier();

        // P3: y-boxsum sliding, 160 tasks = 5 q x 16 cols x 2 halves
        if (tid < 160) {
            const int q   = tid / 32;
            const int r3  = tid - q * 32;
            const int tcx = r3 >> 1;
            const int h   = r3 & 1;
            float c_[16];
#pragma unroll
            for (int k = 0; k < 16; ++k) c_[k] = Rq[q * RQQ + (h * 8 + k) * RQS + tcx];
            float sy = c_[0] + c_[1] + c_[2] + c_[3] + c_[4]
                     + c_[5] + c_[6] + c_[7] + c_[8];
            Sq[q * SQQ + (h * 8) * SQS + tcx] = sy;
#pragma unroll
            for (int i = 1; i < 8; ++i) {
                sy += c_[i + 8] - c_[i - 1];
                Sq[q * SQQ + (h * 8 + i) * SQS + tcx] = sy;
            }
        }
        lds_barrier();

        // P4: cc per output voxel (all 256 threads)
        const float S0 = Sq[0 * SQQ + ty * SQS + tx];
        const float S1 = Sq[1 * SQQ + ty * SQS + tx];
        const float S2 = Sq[2 * SQQ + ty * SQS + tx];
        const float S3 = Sq[3 * SQQ + ty * SQS + tx];
        const float S4 = Sq[4 * SQQ + ty * SQS + tx];
        const float cross = S4 - S0 * S1 * INV729;
        const float Iv    = S2 - S0 * S0 * INV729;
        const float Jv    = S3 - S1 * S1 * INV729;
        acc += (cross * cross) / (Iv * Jv + 1e-5f);
        // Hazards: next P1 writes Zq (last read P2: 2 barriers back),
        // next P2 writes Rq (last read P3: behind next barrier), next P3
        // writes Sq (read here: behind next two barriers). All safe.
    }

    // ---- block reduction (deterministic within block) ----
#pragma unroll
    for (int off = 32; off > 0; off >>= 1) acc += __shfl_down(acc, off);
    __syncthreads();                       // full barrier fine here (no prefetch pending)
    if ((tid & 63) == 0) redbuf[tid >> 6] = acc;
    __syncthreads();
    if (tid == 0) partial[s] = redbuf[0] + redbuf[1] + redbuf[2] + redbuf[3];
}

__global__ __launch_bounds__(256) void ncc_final(
    const float* __restrict__ partial, float* __restrict__ out)
{
    __shared__ float sm[256];
    const int tid = threadIdx.x;
    float v = 0.f;
    for (int i = tid; i < NBLK; i += 256) v += partial[i];
    sm[tid] = v;
    __syncthreads();
#pragma unroll
    for (int w = 128; w > 0; w >>= 1) {
        if (tid < w) sm[tid] += sm[tid + w];
        __syncthreads();
    }
    if (tid == 0) out[0] = 1.0f - sm[0] * (1.0f / (float)TOTAL);
}

extern "C" void kernel_launch(void* const* d_in, const int* in_sizes, int n_in,
                              void* d_out, int out_size, void* d_ws, size_t ws_size,
                              hipStream_t stream)
{
    const float* predict = (const float*)d_in[0];  // J
    const float* target  = (const float*)d_in[1];  // I
    float* partial = (float*)d_ws;                 // 2400 floats (9.6 KB)

    ncc_main<<<dim3(NBLK), 256, 0, stream>>>(predict, target, partial);
    ncc_final<<<1, 256, 0, stream>>>(partial, (float*)d_out);
}